// Round 2
// baseline (475.866 us; speedup 1.0000x reference)
//
#include <hip/hip_runtime.h>
#include <hip/hip_bf16.h>

typedef unsigned short u16;
typedef __bf16 bf16x8 __attribute__((ext_vector_type(8)));
typedef float f32x4 __attribute__((ext_vector_type(4)));

#define B_IMG 128
#define NOBJ  36
#define NNODE (B_IMG * NOBJ)

__device__ __forceinline__ float b2f(u16 u) {
    union { unsigned int i; float f; } v; v.i = ((unsigned int)u) << 16; return v.f;
}
__device__ __forceinline__ u16 f2b(float f) {
    union { float f; unsigned int i; } v; v.f = f;
    unsigned int u = v.i;
    return (u16)((u + 0x7fffu + ((u >> 16) & 1u)) >> 16);   // RNE
}

// ---------------------------------------------------------------------------
// fp32 -> bf16 packer. n4 = elems/4.
// ---------------------------------------------------------------------------
__global__ __launch_bounds__(256)
void conv_mat(const float* __restrict__ src, u16* __restrict__ dst, int n4) {
    const int i = blockIdx.x * 256 + threadIdx.x;
    if (i >= n4) return;
    const float4 f = ((const float4*)src)[i];
    ushort4 o; o.x = f2b(f.x); o.y = f2b(f.y); o.z = f2b(f.z); o.w = f2b(f.w);
    ((ushort4*)dst)[i] = o;
}

// ---------------------------------------------------------------------------
// qe pad-convert: [128,2400] fp32 -> [128,2560] bf16, zero pad cols >= 2400.
// ---------------------------------------------------------------------------
__global__ __launch_bounds__(256)
void conv_pad_qe(const float* __restrict__ src, u16* __restrict__ dst) {
    const int i = blockIdx.x * 256 + threadIdx.x;
    if (i >= 128 * 2560) return;
    const int r = i / 2560, c = i - r * 2560;
    dst[i] = (c < 2400) ? f2b(src[r * 2400 + c]) : (u16)0;
}

// ---------------------------------------------------------------------------
// fused fp32->bf16 convert + transpose: dst[c*R + r] = cvt(src[r*C + c]).
// ---------------------------------------------------------------------------
__global__ __launch_bounds__(256)
void transpose_cvt(const float* __restrict__ src, u16* __restrict__ dst, int R, int C) {
    __shared__ u16 tile[32][33];
    const int bx = blockIdx.x * 32, by = blockIdx.y * 32;
    const int tx = threadIdx.x & 31, ty = threadIdx.x >> 5;   // 32x8
    #pragma unroll
    for (int i = ty; i < 32; i += 8)
        tile[i][tx] = f2b(src[(size_t)(by + i) * C + bx + tx]);
    __syncthreads();
    #pragma unroll
    for (int i = ty; i < 32; i += 8) dst[(size_t)(bx + i) * R + by + tx] = tile[tx][i];
}

// ---------------------------------------------------------------------------
// Wq transpose with K-pad: src [2400,2048] fp32 -> dst [2048,2560] bf16,
// rows (k) >= 2400 zero-filled.  Grid (2048/32, 2560/32).
// ---------------------------------------------------------------------------
__global__ __launch_bounds__(256)
void transpose_cvt_padK(const float* __restrict__ src, u16* __restrict__ dst) {
    __shared__ u16 tile[32][33];
    const int bx = blockIdx.x * 32, by = blockIdx.y * 32;   // bx: n, by: k
    const int tx = threadIdx.x & 31, ty = threadIdx.x >> 5;
    #pragma unroll
    for (int i = ty; i < 32; i += 8) {
        const int k = by + i;
        tile[i][tx] = (k < 2400) ? f2b(src[(size_t)k * 2048 + bx + tx]) : (u16)0;
    }
    __syncthreads();
    #pragma unroll
    for (int i = ty; i < 32; i += 8) dst[(size_t)(bx + i) * 2560 + by + tx] = tile[tx][i];
}

// ---------------------------------------------------------------------------
// TN MFMA GEMM: C[M,N] = A[M,K] * Bt[N,K]^T   (bf16 in, fp32 acc)
// 128x128 tile, BK=32, 4 waves 2x2, per iter 4x4 16x16x32 MFMA.
// 2 stages = 32 KB LDS -> 4 blocks/CU (16 waves/CU).
// EPI: 1 = splitK fp32 partial, 2 = +bias then *qmul -> bf16, 0 = bf16.
// ---------------------------------------------------------------------------
template<int EPI>
__global__ __launch_bounds__(256, 4)
void gemm_tn(const u16* __restrict__ A, const u16* __restrict__ Bt,
             int M, int N, int K, int kLen,
             float* __restrict__ Cf, u16* __restrict__ Cb,
             const float* __restrict__ bias, const float* __restrict__ qmul)
{
    __shared__ __align__(16) u16 lds[2 * 8192];   // 32 KB

    const int t    = threadIdx.x;
    const int lane = t & 63;
    const int wave = t >> 6;
    const int wr = wave >> 1, wc = wave & 1;
    const int quad = lane >> 4, l16 = lane & 15;
    const int rowBase = blockIdx.y * 128;
    const int colBase = blockIdx.x * 128;
    const int k0 = blockIdx.z * kLen;

    // staging: wave w owns rows [w*32, w*32+32); 2 DMA of 16 rows per matrix.
    const u16* gA0 = A  + (size_t)(rowBase + wave * 32 + (lane >> 2)) * K + k0 + (lane & 3) * 8;
    const u16* gA1 = gA0 + 16 * (size_t)K;
    const u16* gB0 = Bt + (size_t)(colBase + wave * 32 + (lane >> 2)) * K + k0 + (lane & 3) * 8;
    const u16* gB1 = gB0 + 16 * (size_t)K;
    const int ro = wave * 1024;   // 32 rows * 32 u16

    int afr[4], bfr[4];
    #pragma unroll
    for (int r = 0; r < 4; r++) afr[r] = (wr * 64 + r * 16 + l16) * 32 + quad * 8;
    #pragma unroll
    for (int c = 0; c < 4; c++) bfr[c] = 4096 + (wc * 64 + c * 16 + l16) * 32 + quad * 8;

    f32x4 acc[4][4];
    #pragma unroll
    for (int r = 0; r < 4; r++)
        #pragma unroll
        for (int c = 0; c < 4; c++)
            acc[r][c] = (f32x4){0.f, 0.f, 0.f, 0.f};

    auto gld = [](const u16* g, u16* s) {
        __builtin_amdgcn_global_load_lds(
            (const __attribute__((address_space(1))) void*)g,
            (__attribute__((address_space(3))) void*)s, 16, 0, 0);
    };
    auto dma_stage = [&](int it, int st) {
        const int kk = it * 32;
        const int bo = st * 8192;
        gld(gA0 + kk, &lds[bo + ro]);
        gld(gA1 + kk, &lds[bo + ro + 512]);
        gld(gB0 + kk, &lds[bo + 4096 + ro]);
        gld(gB1 + kk, &lds[bo + 4096 + ro + 512]);
    };

    const int nIter = kLen >> 5;   // kLen % 32 == 0 for all call sites
    dma_stage(0, 0);

    for (int it = 0; it < nIter; ++it) {
        asm volatile("s_waitcnt vmcnt(0)\n\ts_barrier" ::: "memory");
        if (it + 1 < nIter) dma_stage(it + 1, (it + 1) & 1);
        const int bo = (it & 1) * 8192;
        bf16x8 avf[4], bvf[4];
        #pragma unroll
        for (int r = 0; r < 4; r++) avf[r] = *(const bf16x8*)&lds[bo + afr[r]];
        #pragma unroll
        for (int c = 0; c < 4; c++) bvf[c] = *(const bf16x8*)&lds[bo + bfr[c]];
        #pragma unroll
        for (int r = 0; r < 4; r++)
            #pragma unroll
            for (int c = 0; c < 4; c++)
                acc[r][c] = __builtin_amdgcn_mfma_f32_16x16x32_bf16(avf[r], bvf[c], acc[r][c], 0, 0, 0);
    }

    // epilogue: D row = quad*4+reg, col = l16
    #pragma unroll
    for (int r = 0; r < 4; r++) {
        const int mBase = rowBase + wr * 64 + r * 16 + quad * 4;
        #pragma unroll
        for (int c = 0; c < 4; c++) {
            const int n = colBase + wc * 64 + c * 16 + l16;
            #pragma unroll
            for (int e = 0; e < 4; e++) {
                const int m = mBase + e;
                float v = acc[r][c][e];
                if (EPI == 1) {
                    Cf[((size_t)blockIdx.z * M + m) * N + n] = v;
                } else if (EPI == 2) {
                    v += bias[n];
                    v *= qmul[(size_t)(m / NOBJ) * N + n];
                    Cb[(size_t)m * N + n] = f2b(v);
                } else {
                    Cb[(size_t)m * N + n] = f2b(v);
                }
            }
        }
    }
}

// ---------------------------------------------------------------------------
__global__ __launch_bounds__(256)
void qcombine(const float* __restrict__ p, const float* __restrict__ bias,
              float* __restrict__ q, int MN, int S)
{
    const int i = blockIdx.x * 256 + threadIdx.x;
    float s = 0.f;
    for (int z = 0; z < S; z++) s += p[(size_t)z * MN + i];
    q[i] = s + bias[i & 2047];
}

// ---------------------------------------------------------------------------
// al_s / al_d: per (node, head) dot of h[n,hd,:] with a vecs. Used all layers.
// ---------------------------------------------------------------------------
template<int H, int C>
__global__ __launch_bounds__(H * 64)
void al_kernel(const u16* __restrict__ h, const float* __restrict__ a_s,
               const float* __restrict__ a_d, float* __restrict__ als, float* __restrict__ ald)
{
    const int n = blockIdx.x;
    const int wv = threadIdx.x >> 6, lane = threadIdx.x & 63;
    constexpr int PL = C / 64;
    const u16*   hp  = h   + (size_t)n * (H * C) + wv * C + lane * PL;
    const float* asp = a_s + wv * C + lane * PL;
    const float* adp = a_d + wv * C + lane * PL;
    u16 hb[PL];
    if constexpr (PL == 4) { *(uint2*)hb = *(const uint2*)hp; }
    else                   { *(uint4*)hb = *(const uint4*)hp; }
    float s1 = 0.f, s2 = 0.f;
    #pragma unroll
    for (int i = 0; i < PL; i++) {
        const float hv = b2f(hb[i]);
        s1 += hv * asp[i];
        s2 += hv * adp[i];
    }
    #pragma unroll
    for (int off = 32; off > 0; off >>= 1) {
        s1 += __shfl_down(s1, off);
        s2 += __shfl_down(s2, off);
    }
    if (lane == 0) { als[n * H + wv] = s1; ald[n * H + wv] = s2; }
}

// ---------------------------------------------------------------------------
// alpha_kernel: one wave per (head, image). Thread t<36 = dst row: leaky-relu,
// softmax over 36 src, write [b][hd][36dst][36src] fp32 to global.
// MEAN folds the 1/5 head-mean into alpha (layer 3).
// ---------------------------------------------------------------------------
template<int H, bool MEAN>
__global__ __launch_bounds__(64)
void alpha_kernel(const float* __restrict__ als, const float* __restrict__ ald,
                  float* __restrict__ alphaG)
{
    __shared__ float asl[36];
    const int b = blockIdx.y, hd = blockIdx.x;
    const int nb = b * NOBJ;
    const int t = threadIdx.x;
    if (t < 36) asl[t] = als[(nb + t) * H + hd];
    __syncthreads();
    if (t >= 36) return;
    const float ad = ald[(nb + t) * H + hd];
    float row[36];
    float mx = -1e30f;
    #pragma unroll
    for (int s = 0; s < 36; s++) {
        float v = asl[s] + ad; v = (v > 0.f) ? v : 0.2f * v;
        row[s] = v; mx = fmaxf(mx, v);
    }
    float sum = 0.f;
    #pragma unroll
    for (int s = 0; s < 36; s++) { row[s] = expf(row[s] - mx); sum += row[s]; }
    const float inv = (MEAN ? 0.2f : 1.0f) / (sum + 1e-16f);
    float* o = alphaG + (((size_t)b * H + hd) * 36 + t) * 36;
    #pragma unroll
    for (int s = 0; s < 36; s++) o[s] = row[s] * inv;
}

// ---------------------------------------------------------------------------
// Aggregation, concat layers (1/2): grid (H * C/64, B_IMG), 192 threads.
// Per block: one (head, 64-ch slab). 576 (dst,c4) items = 3 even passes.
// MODE 1: relu(agg+b) -> bf16;  MODE 2: relu(agg+b)+resid -> bf16.
// LDS ~10 KB -> high occupancy.
// ---------------------------------------------------------------------------
template<int H, int C, int MODE>
__global__ __launch_bounds__(192)
void attn_agg(const u16* __restrict__ h, const float* __restrict__ alphaG,
              const float* __restrict__ bias, const u16* __restrict__ resid,
              u16* __restrict__ outb)
{
    constexpr int NSLAB = C / 64;
    __shared__ __align__(16) u16 hl[36 * 64];
    __shared__ float al[36 * 36];
    const int b = blockIdx.y;
    const int hd = blockIdx.x / NSLAB, sl = blockIdx.x - hd * NSLAB;
    const int nb = b * NOBJ, cb = sl * 64;
    const int t = threadIdx.x;

    for (int e = t; e < 36 * 8; e += 192) {
        const int row = e >> 3, col = (e & 7) * 8;
        *(uint4*)&hl[row * 64 + col] =
            *(const uint4*)&h[(size_t)(nb + row) * (H * C) + hd * C + cb + col];
    }
    const float* ap = alphaG + ((size_t)b * H + hd) * 1296;
    for (int e = t; e < 1296; e += 192) al[e] = ap[e];
    __syncthreads();

    #pragma unroll
    for (int p = 0; p < 3; p++) {
        const int e = p * 192 + t;
        const int d = e >> 4, c4 = (e & 15) * 4;
        float a0 = 0, a1 = 0, a2 = 0, a3 = 0;
        for (int s = 0; s < 36; s++) {
            const float av = al[d * 36 + s];
            const ushort4 hv = *(const ushort4*)&hl[s * 64 + c4];
            a0 += av * b2f(hv.x); a1 += av * b2f(hv.y);
            a2 += av * b2f(hv.z); a3 += av * b2f(hv.w);
        }
        const int n = nb + d;
        const size_t base = (size_t)n * (H * C) + hd * C + cb + c4;
        const int bb = hd * C + cb + c4;
        float v0 = a0 + bias[bb + 0];
        float v1 = a1 + bias[bb + 1];
        float v2 = a2 + bias[bb + 2];
        float v3 = a3 + bias[bb + 3];
        v0 = v0 > 0.f ? v0 : 0.f; v1 = v1 > 0.f ? v1 : 0.f;
        v2 = v2 > 0.f ? v2 : 0.f; v3 = v3 > 0.f ? v3 : 0.f;
        if (MODE == 2) {
            v0 += b2f(resid[base + 0]); v1 += b2f(resid[base + 1]);
            v2 += b2f(resid[base + 2]); v3 += b2f(resid[base + 3]);
        }
        outb[base + 0] = f2b(v0); outb[base + 1] = f2b(v1);
        outb[base + 2] = f2b(v2); outb[base + 3] = f2b(v3);
    }
}

// ---------------------------------------------------------------------------
// Aggregation, mean layer (3): grid (512/64, B_IMG), 192 threads.
// Loops 5 heads, register-accumulates (0.2 folded into alpha), +b3 -> fp32.
// ---------------------------------------------------------------------------
__global__ __launch_bounds__(192)
void attn_agg_mean(const u16* __restrict__ h, const float* __restrict__ alphaG,
                   const float* __restrict__ b3, float* __restrict__ outp)
{
    __shared__ __align__(16) u16 hl[36 * 64];
    __shared__ float al[36 * 36];
    const int b = blockIdx.y, sl = blockIdx.x;
    const int nb = b * NOBJ, cb = sl * 64;
    const int t = threadIdx.x;

    float acc[3][4] = {};
    for (int hd = 0; hd < 5; hd++) {
        if (hd) __syncthreads();   // protect hl/al overwrite
        for (int e = t; e < 36 * 8; e += 192) {
            const int row = e >> 3, col = (e & 7) * 8;
            *(uint4*)&hl[row * 64 + col] =
                *(const uint4*)&h[(size_t)(nb + row) * 2560 + hd * 512 + cb + col];
        }
        const float* ap = alphaG + ((size_t)b * 5 + hd) * 1296;
        for (int e = t; e < 1296; e += 192) al[e] = ap[e];
        __syncthreads();
        #pragma unroll
        for (int p = 0; p < 3; p++) {
            const int e = p * 192 + t;
            const int d = e >> 4, c4 = (e & 15) * 4;
            for (int s = 0; s < 36; s++) {
                const float av = al[d * 36 + s];
                const ushort4 hv = *(const ushort4*)&hl[s * 64 + c4];
                acc[p][0] += av * b2f(hv.x); acc[p][1] += av * b2f(hv.y);
                acc[p][2] += av * b2f(hv.z); acc[p][3] += av * b2f(hv.w);
            }
        }
    }
    #pragma unroll
    for (int p = 0; p < 3; p++) {
        const int e = p * 192 + t;
        const int d = e >> 4, c4 = (e & 15) * 4;
        #pragma unroll
        for (int j = 0; j < 4; j++)
            outp[(size_t)(nb + d) * 512 + cb + c4 + j] = acc[p][j] + b3[cb + c4 + j];
    }
}

// ---------------------------------------------------------------------------
// All inputs fp32, output fp32.  Workspace ~65.6 MB, lifetime-packed:
//  E: qe_c(padded 2560) 0.66M | of_c 18.87M
//  A: WqT(2048x2560) -> (qpart @ +10.5M) -> x -> g1 -> h3   (23.59M)
//  B: WvT | q(@ +8.39M) -> W1T -> W2T -> g2                 ( 9.44M)
//  C: h1 -> h2 -> W3T                                       ( 9.44M)
//  D: als, ald | F: alphaG (3.32M)
// ---------------------------------------------------------------------------
extern "C" void kernel_launch(void* const* d_in, const int* in_sizes, int n_in,
                              void* d_out, int out_size, void* d_ws, size_t ws_size,
                              hipStream_t stream)
{
    const float* qe  = (const float*)d_in[0];    // [128,2400]
    const float* of  = (const float*)d_in[1];    // [4608,2048]
    const float* Wq  = (const float*)d_in[3];    // [2400,2048]
    const float* bq  = (const float*)d_in[4];
    const float* Wv  = (const float*)d_in[5];    // [2048,2048]
    const float* bv  = (const float*)d_in[6];
    const float* W1  = (const float*)d_in[7];    // [2048,1024]
    const float* a1s = (const float*)d_in[8];
    const float* a1d = (const float*)d_in[9];
    const float* b1  = (const float*)d_in[10];
    const float* W2  = (const float*)d_in[11];   // [1024,1024]
    const float* a2s = (const float*)d_in[12];
    const float* a2d = (const float*)d_in[13];
    const float* b2  = (const float*)d_in[14];
    const float* W3  = (const float*)d_in[15];   // [1024,2560]
    const float* a3s = (const float*)d_in[16];
    const float* a3d = (const float*)d_in[17];
    const float* b3  = (const float*)d_in[18];
    float* out = (float*)d_out;
    (void)ws_size; (void)in_sizes; (void)n_in; (void)out_size;

    char* W0 = (char*)d_ws;
    size_t off = 0;
    auto alloc = [&](size_t bytes) -> char* {
        char* p = W0 + off; off += (bytes + 255) & ~(size_t)255; return p;
    };
    u16* qe_c = (u16*)alloc(128ull * 2560 * 2);
    u16* of_c = (u16*)alloc(4608ull * 2048 * 2);
    const size_t szA = 4608ull * 2560 * 2;
    const size_t szB = 4608ull * 1024 * 2;
    const size_t szC = 4608ull * 1024 * 2;
    char* Abase = alloc(szA);
    char* Bbase = alloc(szB);
    char* Cbase = alloc(szC);
    char* Dbase = alloc((size_t)NNODE * 5 * 4 * 2);
    float* alphaG = (float*)alloc(128ull * 5 * 36 * 36 * 4);   // 3.32 MB

    u16*   WqT   = (u16*)Abase;                           // [2048,2560] S1-S2
    float* qpart = (float*)(Abase + 2048ull * 2560 * 2);  // S2-S3 (5.2MB fits: 10.5+5.2<23.6)
    u16*   x     = (u16*)Abase;                           // S5-S7
    u16*   g1    = (u16*)Abase;                           // S9-S13
    u16*   h3    = (u16*)Abase;                           // S15-S17
    u16*   WvT   = (u16*)Bbase;                           // S4-S5
    float* q     = (float*)(Bbase + 2048ull * 2048 * 2);  // S3-S5
    u16*   W1T   = (u16*)Bbase;                           // S6-S7
    u16*   W2T   = (u16*)Bbase;                           // S10-S11
    u16*   g2    = (u16*)Bbase;                           // S13-S15
    u16*   h1    = (u16*)Cbase;                           // S7-S9
    u16*   h2    = (u16*)Cbase;                           // S11-S13
    u16*   W3T   = (u16*)Cbase;                           // S14-S15
    float* als   = (float*)Dbase;
    float* ald   = (float*)(Dbase + (size_t)NNODE * 5 * 4);

    // S0: canonicalize activations to bf16 (qe K-padded to 2560)
    conv_pad_qe<<<(128 * 2560 + 255) / 256, 256, 0, stream>>>(qe, qe_c);
    conv_mat<<<(4608 * 2048 / 4 + 255) / 256, 256, 0, stream>>>(of, of_c, 4608 * 2048 / 4);

    // S1-S3: q = qe @ Wq + bq   (K padded 2400->2560, splitK=5 x 512)
    transpose_cvt_padK<<<dim3(64, 80), 256, 0, stream>>>(Wq, WqT);
    gemm_tn<1><<<dim3(16, 1, 5), 256, 0, stream>>>(qe_c, WqT, 128, 2048, 2560, 512,
                                                   qpart, nullptr, nullptr, nullptr);
    qcombine<<<dim3(128 * 2048 / 256), 256, 0, stream>>>(qpart, bq, q, 128 * 2048, 5);

    // S4-S5: x = (of @ Wv + bv) * q_rep
    transpose_cvt<<<dim3(64, 64), 256, 0, stream>>>(Wv, WvT, 2048, 2048);
    gemm_tn<2><<<dim3(16, 36, 1), 256, 0, stream>>>(of_c, WvT, 4608, 2048, 2048, 2048,
                                                    nullptr, x, bv, q);

    // S6-S9: layer 1
    transpose_cvt<<<dim3(32, 64), 256, 0, stream>>>(W1, W1T, 2048, 1024);
    gemm_tn<0><<<dim3(8, 36, 1), 256, 0, stream>>>(x, W1T, 4608, 1024, 2048, 2048,
                                                   nullptr, h1, nullptr, nullptr);
    al_kernel<4, 256><<<dim3(NNODE), 256, 0, stream>>>(h1, a1s, a1d, als, ald);
    alpha_kernel<4, false><<<dim3(4, B_IMG), 64, 0, stream>>>(als, ald, alphaG);
    attn_agg<4, 256, 1><<<dim3(16, B_IMG), 192, 0, stream>>>(h1, alphaG, b1, nullptr, g1);

    // S10-S13: layer 2 (+ residual g1)
    transpose_cvt<<<dim3(32, 32), 256, 0, stream>>>(W2, W2T, 1024, 1024);
    gemm_tn<0><<<dim3(8, 36, 1), 256, 0, stream>>>(g1, W2T, 4608, 1024, 1024, 1024,
                                                   nullptr, h2, nullptr, nullptr);
    al_kernel<4, 256><<<dim3(NNODE), 256, 0, stream>>>(h2, a2s, a2d, als, ald);
    alpha_kernel<4, false><<<dim3(4, B_IMG), 64, 0, stream>>>(als, ald, alphaG);
    attn_agg<4, 256, 2><<<dim3(16, B_IMG), 192, 0, stream>>>(h2, alphaG, b2, g1, g2);

    // S14-S17: layer 3 (5 heads, mean + b3) -> fp32 out
    transpose_cvt<<<dim3(80, 32), 256, 0, stream>>>(W3, W3T, 1024, 2560);
    gemm_tn<0><<<dim3(20, 36, 1), 256, 0, stream>>>(g2, W3T, 4608, 2560, 1024, 1024,
                                                    nullptr, h3, nullptr, nullptr);
    al_kernel<5, 512><<<dim3(NNODE), 320, 0, stream>>>(h3, a3s, a3d, als, ald);
    alpha_kernel<5, true><<<dim3(5, B_IMG), 64, 0, stream>>>(als, ald, alphaG);
    attn_agg_mean<<<dim3(8, B_IMG), 192, 0, stream>>>(h3, alphaG, b3, out);
}